// Round 12
// baseline (341.873 us; speedup 1.0000x reference)
//
#include <hip/hip_runtime.h>
#include <math.h>

#define N_NODES 50000
#define N_EDGES 800000
#define ETOT    (N_EDGES + N_NODES)
#define FDIM    256
#define HDIM    256
#define NGRAPH  64
#define C_OUT   10
#define BN_EPS  1e-5f
#define ATT_SLOPE 0.2f
#define ACT_SLOPE 0.01f

#define NBUCK   ((N_NODES + 15) / 16)    // 3125 buckets of 16 dsts
#define BCAP    512                      // bucket capacity (mean 272)
#define SORT_NB 192                      // blocks for count/scatter passes
#define EPB     ((ETOT + SORT_NB - 1) / SORT_NB)

typedef __attribute__((ext_vector_type(8))) short bf16x8;
typedef __attribute__((ext_vector_type(4))) float f32x4;

__device__ __forceinline__ float leaky(float x, float s) { return x >= 0.f ? x : s * x; }

__device__ __forceinline__ float bf2f(unsigned short u) {
    return __uint_as_float((unsigned)u << 16);
}
__device__ __forceinline__ unsigned short f2bf(float f) {
    unsigned u = __float_as_uint(f);
    u += 0x7FFF + ((u >> 16) & 1);   // RNE
    return (unsigned short)(u >> 16);
}
__device__ __forceinline__ float rlF(float a, int j) {
    return __uint_as_float(__builtin_amdgcn_readlane(__float_as_uint(a), j));
}

// async global->LDS, 16B per lane; dst must be wave-uniform base (lane*16 auto-offset)
__device__ __forceinline__ void gload_lds16(const unsigned short* g, unsigned short* l) {
    __builtin_amdgcn_global_load_lds((const __attribute__((address_space(1))) void*)(g),
                                     (__attribute__((address_space(3))) void*)(l), 16, 0, 0);
}

__device__ __forceinline__ void edge_sd(const int* __restrict__ ei, int e, int& s, int& d) {
    if (e < N_EDGES) { s = ei[e]; d = ei[N_EDGES + e]; }
    else             { s = e - N_EDGES; d = s; }
}

// ---------------- weight prep: W1^T->bf16 (W2 handled by fold_bn) ----------------
__global__ __launch_bounds__(256) void prep_w(const float* __restrict__ W1,
                                              unsigned short* __restrict__ Wt1) {
    int idx = blockIdx.x * 256 + threadIdx.x;
    int n = idx >> 8, k = idx & 255;
    Wt1[idx] = f2bf(W1[k * 256 + n]);
}

// ---------------- BN fold: Wt2f[n][k] = bf16(scale[k]*W2[k][n]); cbias[n] = sum_k shift[k]*W2[k][n]
__global__ __launch_bounds__(256) void fold_bn(const float* __restrict__ W2,
                                               const float* __restrict__ scale,
                                               const float* __restrict__ shift,
                                               unsigned short* __restrict__ Wt2f,
                                               float* __restrict__ cbias) {
    __shared__ float red[256];
    int n = blockIdx.x, k = threadIdx.x;
    float w = W2[k * 256 + n];
    Wt2f[n * 256 + k] = f2bf(w * scale[k]);
    red[k] = w * shift[k];
    __syncthreads();
    #pragma unroll
    for (int off = 128; off; off >>= 1) {
        if (k < off) red[k] += red[k + off];
        __syncthreads();
    }
    if (k == 0) cbias[n] = red[0];
}

// ---------------- bf16 MFMA GEMM, 128x256 row-strip tile, 512 threads (8 waves 2x4) ----------------
template<bool FROMF32>
__global__ __launch_bounds__(512) void gemm_bf16(const void* __restrict__ Avp,
                                                 const unsigned short* __restrict__ Bt,
                                                 const float* __restrict__ cbias,
                                                 const float* __restrict__ avs,
                                                 const float* __restrict__ avd,
                                                 float* __restrict__ es,
                                                 float* __restrict__ ed,
                                                 unsigned short* __restrict__ C, int M) {
    __shared__ unsigned short Al[128 * 64];
    __shared__ unsigned short Bl[256 * 64];
    __shared__ float lred[4][128][2];
    const int tid = threadIdx.x;
    const int lane = tid & 63;
    const int wid = tid >> 6;            // 0..7
    const int wm = wid >> 2, wn = wid & 3;
    const int row0 = blockIdx.x * 128;
    const int g = lane >> 4, rl = lane & 15;

    f32x4 acc[4][4];
    #pragma unroll
    for (int m = 0; m < 4; ++m)
        #pragma unroll
        for (int n = 0; n < 4; ++n)
            acc[m][n] = (f32x4){0.f, 0.f, 0.f, 0.f};

    for (int kk = 0; kk < 256; kk += 64) {
        // ---- stage A ----
        if (FROMF32) {
            const float* Af = (const float*)Avp;
            #pragma unroll
            for (int j = 0; j < 2; ++j) {
                int idx = j * 512 + tid;
                int row = idx >> 3, chunk = idx & 7;
                int sc = chunk ^ (row & 7);
                int grow = row0 + row; if (grow >= M) grow = M - 1;
                float4 f0 = *(const float4*)&Af[(size_t)grow * 256 + kk + chunk * 8];
                float4 f1 = *(const float4*)&Af[(size_t)grow * 256 + kk + chunk * 8 + 4];
                uint4 av;
                unsigned short* p = (unsigned short*)&av;
                p[0] = f2bf(f0.x); p[1] = f2bf(f0.y); p[2] = f2bf(f0.z); p[3] = f2bf(f0.w);
                p[4] = f2bf(f1.x); p[5] = f2bf(f1.y); p[6] = f2bf(f1.z); p[7] = f2bf(f1.w);
                *(uint4*)&Al[row * 64 + sc * 8] = av;
            }
        } else {
            const unsigned short* Ab = (const unsigned short*)Avp;
            #pragma unroll
            for (int j = 0; j < 2; ++j) {
                int rowBase = (j * 8 + wid) * 8;
                int row = rowBase + (lane >> 3);
                int grow = row0 + row; if (grow >= M) grow = M - 1;
                int chunk = (lane & 7) ^ (row & 7);
                gload_lds16(&Ab[(size_t)grow * 256 + kk + chunk * 8], &Al[rowBase * 64]);
            }
        }
        // ---- stage B via global_load_lds (pre-swizzled source) ----
        #pragma unroll
        for (int j = 0; j < 4; ++j) {
            int colBase = (j * 8 + wid) * 8;
            int col = colBase + (lane >> 3);
            int chunk = (lane & 7) ^ (col & 7);
            gload_lds16(&Bt[(size_t)col * 256 + kk + chunk * 8], &Bl[colBase * 64]);
        }
        __syncthreads();
        #pragma unroll
        for (int ks = 0; ks < 2; ++ks) {
            bf16x8 af[4], bfr[4];
            int chunk = ks * 4 + g;
            #pragma unroll
            for (int m = 0; m < 4; ++m) {
                int row = wm * 64 + m * 16 + rl;
                int sc = chunk ^ (row & 7);
                af[m] = *(const bf16x8*)&Al[row * 64 + sc * 8];
            }
            #pragma unroll
            for (int n = 0; n < 4; ++n) {
                int col = wn * 64 + n * 16 + rl;
                int sc = chunk ^ (col & 7);
                bfr[n] = *(const bf16x8*)&Bl[col * 64 + sc * 8];
            }
            #pragma unroll
            for (int m = 0; m < 4; ++m)
                #pragma unroll
                for (int n = 0; n < 4; ++n)
                    acc[m][n] = __builtin_amdgcn_mfma_f32_16x16x32_bf16(af[m], bfr[n], acc[m][n], 0, 0, 0);
        }
        __syncthreads();
    }
    // rank-1 BN-fold bias (conv2 only)
    if (cbias != nullptr) {
        #pragma unroll
        for (int n = 0; n < 4; ++n) {
            float cb = cbias[wn * 64 + n * 16 + rl];
            #pragma unroll
            for (int m = 0; m < 4; ++m)
                #pragma unroll
                for (int r = 0; r < 4; ++r)
                    acc[m][n][r] += cb;
        }
    }
    // C write (bf16): C/D frag layout col=lane&15, row=(lane>>4)*4+reg
    #pragma unroll
    for (int m = 0; m < 4; ++m) {
        #pragma unroll
        for (int n = 0; n < 4; ++n) {
            int col = wn * 64 + n * 16 + rl;
            #pragma unroll
            for (int r = 0; r < 4; ++r) {
                int row = row0 + wm * 64 + m * 16 + g * 4 + r;
                if (row < M) C[(size_t)row * 256 + col] = f2bf(acc[m][n][r]);
            }
        }
    }
    // fused attention dots: 16-lane reduce -> LDS (4 wn groups) -> exact plain stores
    float as_[4], ad_[4];
    #pragma unroll
    for (int n = 0; n < 4; ++n) {
        int col = wn * 64 + n * 16 + rl;
        as_[n] = avs[col]; ad_[n] = avd[col];
    }
    #pragma unroll
    for (int m = 0; m < 4; ++m) {
        #pragma unroll
        for (int r = 0; r < 4; ++r) {
            float ps = 0.f, pd = 0.f;
            #pragma unroll
            for (int n = 0; n < 4; ++n) {
                float v = acc[m][n][r];
                ps += v * as_[n]; pd += v * ad_[n];
            }
            #pragma unroll
            for (int off = 1; off < 16; off <<= 1) {
                ps += __shfl_xor(ps, off);
                pd += __shfl_xor(pd, off);
            }
            if (rl == 0) {
                int lr = wm * 64 + m * 16 + g * 4 + r;
                lred[wn][lr][0] = ps;
                lred[wn][lr][1] = pd;
            }
        }
    }
    __syncthreads();
    if (tid < 128) {
        int row = row0 + tid;
        if (row < M) {
            es[row] = (lred[0][tid][0] + lred[1][tid][0]) + (lred[2][tid][0] + lred[3][tid][0]);
            ed[row] = (lred[0][tid][1] + lred[1][tid][1]) + (lred[2][tid][1] + lred[3][tid][1]);
        }
    }
}

// ---------------- atomic-free CSR build (2-pass LDS-histogram bucket sort) ----------------
__global__ __launch_bounds__(256) void count_k(const int* __restrict__ ei,
                                               int* __restrict__ hist2d) {
    __shared__ int lcnt[NBUCK];
    int t = threadIdx.x, blk = blockIdx.x;
    for (int i = t; i < NBUCK; i += 256) lcnt[i] = 0;
    __syncthreads();
    int e0 = blk * EPB, e1 = min(e0 + EPB, ETOT);
    for (int e = e0 + t; e < e1; e += 256) {
        int d = (e < N_EDGES) ? ei[N_EDGES + e] : (e - N_EDGES);
        atomicAdd(&lcnt[d >> 4], 1);
    }
    __syncthreads();
    int* outp = hist2d + blk * NBUCK;
    for (int i = t; i < NBUCK; i += 256) outp[i] = lcnt[i];
}

__global__ __launch_bounds__(256) void colscan_k(int* __restrict__ hist2d,
                                                 int* __restrict__ bcnt) {
    int col = blockIdx.x * 256 + threadIdx.x;
    if (col >= NBUCK) return;
    int run = 0;
    for (int b = 0; b < SORT_NB; ++b) {
        int idx = b * NBUCK + col;
        int c = hist2d[idx];
        hist2d[idx] = run;
        run += c;
    }
    bcnt[col] = run;
}

__global__ __launch_bounds__(256) void scan_buckets(const int* __restrict__ bcnt,
                                                    int* __restrict__ bbase,
                                                    int* __restrict__ row_ptr) {
    __shared__ int s[256];
    constexpr int PER = (NBUCK + 255) / 256;   // 13
    int t = threadIdx.x;
    int loc[PER];
    int sum = 0;
    #pragma unroll
    for (int i = 0; i < PER; ++i) {
        int idx = t * PER + i;
        loc[i] = sum;
        sum += (idx < NBUCK) ? bcnt[idx] : 0;
    }
    s[t] = sum;
    __syncthreads();
    #pragma unroll
    for (int off = 1; off < 256; off <<= 1) {
        int add = (t >= off) ? s[t - off] : 0;
        __syncthreads();
        s[t] += add;
        __syncthreads();
    }
    int base = (t > 0) ? s[t - 1] : 0;
    #pragma unroll
    for (int i = 0; i < PER; ++i) {
        int idx = t * PER + i;
        if (idx < NBUCK) bbase[idx] = base + loc[i];
    }
    if (t == 0) row_ptr[N_NODES] = ETOT;
}

__global__ __launch_bounds__(256) void scatter2_k(const int* __restrict__ ei,
                                                  const int* __restrict__ hist2d,
                                                  int* __restrict__ bstore) {
    __shared__ int lcur[NBUCK];
    __shared__ int lbase[NBUCK];
    int t = threadIdx.x, blk = blockIdx.x;
    const int* boff = hist2d + blk * NBUCK;
    for (int i = t; i < NBUCK; i += 256) { lcur[i] = 0; lbase[i] = boff[i]; }
    __syncthreads();
    int e0 = blk * EPB, e1 = min(e0 + EPB, ETOT);
    for (int e = e0 + t; e < e1; e += 256) {
        int s, d; edge_sd(ei, e, s, d);
        int b = d >> 4;
        int r = atomicAdd(&lcur[b], 1);
        int pos = lbase[b] + r;
        if (pos < BCAP) bstore[(size_t)b * BCAP + pos] = s | ((d & 15) << 16);
    }
}

__global__ __launch_bounds__(256) void place_k(const int* __restrict__ bcnt,
                                               const int* __restrict__ bbase,
                                               const int* __restrict__ bstore,
                                               int* __restrict__ row_ptr,
                                               int* __restrict__ csr_src) {
    __shared__ int h16[16], e16[16], c16[16];
    int b = blockIdx.x, t = threadIdx.x;
    if (t < 16) { h16[t] = 0; c16[t] = 0; }
    __syncthreads();
    int sz = bcnt[b]; if (sz > BCAP) sz = BCAP;
    int base = bbase[b];
    const int* bs = bstore + (size_t)b * BCAP;
    int v0 = -1, v1 = -1;
    if (t < sz)       { v0 = bs[t];       atomicAdd(&h16[v0 >> 16], 1); }
    if (t + 256 < sz) { v1 = bs[t + 256]; atomicAdd(&h16[v1 >> 16], 1); }
    __syncthreads();
    if (t == 0) {
        int run = 0;
        #pragma unroll
        for (int j = 0; j < 16; ++j) { e16[j] = run; run += h16[j]; }
    }
    __syncthreads();
    if (t < 16) {
        int d = b * 16 + t;
        if (d < N_NODES) row_ptr[d] = base + e16[t];
    }
    if (v0 >= 0) {
        int dl = v0 >> 16;
        int pos = base + e16[dl] + atomicAdd(&c16[dl], 1);
        csr_src[pos] = v0 & 0xFFFF;
    }
    if (v1 >= 0) {
        int dl = v1 >> 16;
        int pos = base + e16[dl] + atomicAdd(&c16[dl], 1);
        csr_src[pos] = v1 & 0xFFFF;
    }
}

// ---------------- full-wave gather helper (fallback path): 4-deep ILP, readlane ----------------
__device__ __forceinline__ void gather4(const unsigned short* __restrict__ hl,
                                        float a, int src, int lim,
                                        float4& A0, float4& A1, float4& A2, float4& A3) {
    int j = 0;
    for (; j + 3 < lim; j += 4) {
        float w0 = rlF(a, j + 0), w1 = rlF(a, j + 1), w2 = rlF(a, j + 2), w3 = rlF(a, j + 3);
        int s0 = __builtin_amdgcn_readlane(src, j + 0);
        int s1 = __builtin_amdgcn_readlane(src, j + 1);
        int s2 = __builtin_amdgcn_readlane(src, j + 2);
        int s3 = __builtin_amdgcn_readlane(src, j + 3);
        ushort4 v0 = *(const ushort4*)&hl[(size_t)s0 * HDIM];
        ushort4 v1 = *(const ushort4*)&hl[(size_t)s1 * HDIM];
        ushort4 v2 = *(const ushort4*)&hl[(size_t)s2 * HDIM];
        ushort4 v3 = *(const ushort4*)&hl[(size_t)s3 * HDIM];
        A0.x += w0 * bf2f(v0.x); A0.y += w0 * bf2f(v0.y); A0.z += w0 * bf2f(v0.z); A0.w += w0 * bf2f(v0.w);
        A1.x += w1 * bf2f(v1.x); A1.y += w1 * bf2f(v1.y); A1.z += w1 * bf2f(v1.z); A1.w += w1 * bf2f(v1.w);
        A2.x += w2 * bf2f(v2.x); A2.y += w2 * bf2f(v2.y); A2.z += w2 * bf2f(v2.z); A2.w += w2 * bf2f(v2.w);
        A3.x += w3 * bf2f(v3.x); A3.y += w3 * bf2f(v3.y); A3.z += w3 * bf2f(v3.z); A3.w += w3 * bf2f(v3.w);
    }
    for (; j < lim; ++j) {
        float w = rlF(a, j);
        int s = __builtin_amdgcn_readlane(src, j);
        ushort4 v = *(const ushort4*)&hl[(size_t)s * HDIM];
        A0.x += w * bf2f(v.x); A0.y += w * bf2f(v.y); A0.z += w * bf2f(v.z); A0.w += w * bf2f(v.w);
    }
}

// full-wave processing of one dst (fallback for deg>32)
__device__ void dst_one_fullwave(int d, int lane,
                                 const int* __restrict__ row_ptr,
                                 const int* __restrict__ csr_src,
                                 const float* __restrict__ es,
                                 const float* __restrict__ ed,
                                 const unsigned short* __restrict__ h,
                                 const float* __restrict__ bias,
                                 unsigned short* __restrict__ outb) {
    float4 b4 = *(const float4*)&bias[lane * 4];
    int start = row_ptr[d], end = row_ptr[d + 1];
    int deg = end - start;
    float edv = ed[d];
    const unsigned short* hl = h + lane * 4;
    float4 A0 = {0,0,0,0}, A1 = {0,0,0,0}, A2 = {0,0,0,0}, A3 = {0,0,0,0};
    float ssum = 0.f;
    if (deg > 0 && deg <= 64) {
        int src = 0; float v = -INFINITY;
        if (lane < deg) {
            src = csr_src[start + lane];
            v = leaky(es[src] + edv, ATT_SLOPE);
        }
        float m = v;
        #pragma unroll
        for (int off = 32; off; off >>= 1) m = fmaxf(m, __shfl_xor(m, off));
        float a = (lane < deg) ? expf(v - m) : 0.f;
        ssum = a;
        gather4(hl, a, src, deg, A0, A1, A2, A3);
    } else if (deg > 64) {
        float m = -INFINITY;
        for (int base = start; base < end; base += 64) {
            int idx = base + lane;
            if (idx < end) m = fmaxf(m, leaky(es[csr_src[idx]] + edv, ATT_SLOPE));
        }
        #pragma unroll
        for (int off = 32; off; off >>= 1) m = fmaxf(m, __shfl_xor(m, off));
        for (int base = start; base < end; base += 64) {
            int idx = base + lane;
            int src = 0; float a = 0.f;
            if (idx < end) {
                src = csr_src[idx];
                a = expf(leaky(es[src] + edv, ATT_SLOPE) - m);
            }
            ssum += a;
            int lim = end - base; if (lim > 64) lim = 64;
            gather4(hl, a, src, lim, A0, A1, A2, A3);
        }
    } else {
        ssum = 1.f;
    }
    #pragma unroll
    for (int off = 32; off; off >>= 1) ssum += __shfl_xor(ssum, off);
    float inv = (deg > 0) ? (1.f / ssum) : 0.f;
    float4 acc;
    acc.x = (A0.x + A1.x) + (A2.x + A3.x);
    acc.y = (A0.y + A1.y) + (A2.y + A3.y);
    acc.z = (A0.z + A1.z) + (A2.z + A3.z);
    acc.w = (A0.w + A1.w) + (A2.w + A3.w);
    ushort4 o;
    o.x = f2bf(leaky(acc.x * inv + b4.x, ACT_SLOPE));
    o.y = f2bf(leaky(acc.y * inv + b4.y, ACT_SLOPE));
    o.z = f2bf(leaky(acc.z * inv + b4.z, ACT_SLOPE));
    o.w = f2bf(leaky(acc.w * inv + b4.w, ACT_SLOPE));
    *(ushort4*)&outb[(size_t)d * HDIM + lane * 4] = o;
}

// ---------------- fused softmax+gather: 2 dsts per wave (half-wave each, 16B/lane) ----------------
// 8 dsts per 256-thread block; 6250 blocks cover 50000 exactly.
__global__ __launch_bounds__(256) void dst_agg(const int* __restrict__ row_ptr,
                                               const int* __restrict__ csr_src,
                                               const float* __restrict__ es,
                                               const float* __restrict__ ed,
                                               const unsigned short* __restrict__ h,
                                               const float* __restrict__ bias,
                                               unsigned short* __restrict__ outb) {
    int wid = threadIdx.x >> 6;
    int lane = threadIdx.x & 63;
    int d0 = blockIdx.x * 8 + wid * 2;
    int d1 = d0 + 1;
    int rp0 = row_ptr[d0], rp1 = row_ptr[d1], rp2 = row_ptr[d1 + 1];
    int deg0 = rp1 - rp0, deg1 = rp2 - rp1;

    if (deg0 > 0 && deg0 <= 32 && deg1 > 0 && deg1 <= 32) {
        // fast path: half-wave per dst
        int half = lane >> 5, hl = lane & 31;
        int myd    = half ? d1 : d0;
        int mydeg  = half ? deg1 : deg0;
        int mystart= half ? rp1 : rp0;
        float edv = ed[myd];
        int src = 0; float v = -INFINITY;
        if (hl < mydeg) {
            src = csr_src[mystart + hl];
            v = leaky(es[src] + edv, ATT_SLOPE);
        }
        float m = v;
        #pragma unroll
        for (int off = 16; off; off >>= 1) m = fmaxf(m, __shfl_xor(m, off));
        float a = (hl < mydeg) ? expf(v - m) : 0.f;
        float ssum = a;
        #pragma unroll
        for (int off = 16; off; off >>= 1) ssum += __shfl_xor(ssum, off);
        // gather: each iteration, each half consumes one of its own edges; 16B/lane
        int iters = max(deg0, deg1);
        float accv[8] = {0.f, 0.f, 0.f, 0.f, 0.f, 0.f, 0.f, 0.f};
        const unsigned short* hp = h + hl * 8;
        int j = 0;
        for (; j + 1 < iters; j += 2) {
            float wA = __shfl(a, half * 32 + j);
            int   sA = __shfl(src, half * 32 + j);
            float wB = __shfl(a, half * 32 + j + 1);
            int   sB = __shfl(src, half * 32 + j + 1);
            bool pA = (j < mydeg), pB = (j + 1 < mydeg);
            if (pA) {
                uint4 hv = *(const uint4*)&hp[(size_t)sA * HDIM];
                const unsigned short* p = (const unsigned short*)&hv;
                #pragma unroll
                for (int k = 0; k < 8; ++k) accv[k] += wA * bf2f(p[k]);
            }
            if (pB) {
                uint4 hv = *(const uint4*)&hp[(size_t)sB * HDIM];
                const unsigned short* p = (const unsigned short*)&hv;
                #pragma unroll
                for (int k = 0; k < 8; ++k) accv[k] += wB * bf2f(p[k]);
            }
        }
        if (j < iters) {
            float wA = __shfl(a, half * 32 + j);
            int   sA = __shfl(src, half * 32 + j);
            if (j < mydeg) {
                uint4 hv = *(const uint4*)&hp[(size_t)sA * HDIM];
                const unsigned short* p = (const unsigned short*)&hv;
                #pragma unroll
                for (int k = 0; k < 8; ++k) accv[k] += wA * bf2f(p[k]);
            }
        }
        float inv = 1.f / ssum;
        float4 bA = *(const float4*)&bias[hl * 8];
        float4 bB = *(const float4*)&bias[hl * 8 + 4];
        float bb[8] = {bA.x, bA.y, bA.z, bA.w, bB.x, bB.y, bB.z, bB.w};
        unsigned short o[8];
        #pragma unroll
        for (int k = 0; k < 8; ++k)
            o[k] = f2bf(leaky(accv[k] * inv + bb[k], ACT_SLOPE));
        *(uint4*)&outb[(size_t)myd * HDIM + hl * 8] = *(uint4*)o;
    } else {
        // rare: process each dst with the full wave
        dst_one_fullwave(d0, lane, row_ptr, csr_src, es, ed, h, bias, outb);
        dst_one_fullwave(d1, lane, row_ptr, csr_src, es, ed, h, bias, outb);
    }
}

// column sum/sumsq over bf16 activations (read-only)
__global__ __launch_bounds__(256) void bn_stats_k(const unsigned short* __restrict__ buf,
                                                  float* __restrict__ csum,
                                                  float* __restrict__ csq) {
    int t = threadIdx.x;
    int rows_per = (N_NODES + gridDim.x - 1) / gridDim.x;
    int r0 = blockIdx.x * rows_per;
    int r1 = min(r0 + rows_per, N_NODES);
    float sum = 0.f, sq = 0.f;
    for (int r = r0; r < r1; ++r) {
        float v = bf2f(buf[(size_t)r * HDIM + t]);
        sum += v; sq += v * v;
    }
    atomicAdd(&csum[t], sum);
    atomicAdd(&csq[t], sq);
}

__global__ __launch_bounds__(256) void bn_param(const float* __restrict__ csum,
                                                const float* __restrict__ csq,
                                                const float* __restrict__ gamma,
                                                const float* __restrict__ beta,
                                                float* __restrict__ scale,
                                                float* __restrict__ shift) {
    int t = threadIdx.x;
    float mean = csum[t] / (float)N_NODES;
    float var = csq[t] / (float)N_NODES - mean * mean;
    float sc = gamma[t] * rsqrtf(var + BN_EPS);
    scale[t] = sc;
    shift[t] = beta[t] - mean * sc;
}

// run-length pooled segment add over bf16 activations
__global__ __launch_bounds__(256) void post_pool(const unsigned short* __restrict__ buf,
                                                 const int* __restrict__ batch,
                                                 float* __restrict__ gsum,
                                                 float* __restrict__ gcnt) {
    int t = threadIdx.x;
    int rows_per = (N_NODES + gridDim.x - 1) / gridDim.x;
    int r0 = blockIdx.x * rows_per;
    int r1 = min(r0 + rows_per, N_NODES);
    if (r0 >= r1) return;
    int curb = -1; float acc = 0.f; int cnt = 0;
    for (int r = r0; r < r1; ++r) {
        int bb = batch[r];
        if (bb != curb) {
            if (curb >= 0) {
                atomicAdd(&gsum[(size_t)curb * HDIM + t], acc);
                if (t == 0) atomicAdd(&gcnt[curb], (float)cnt);
            }
            curb = bb; acc = 0.f; cnt = 0;
        }
        acc += bf2f(buf[(size_t)r * HDIM + t]);
        cnt++;
    }
    if (curb >= 0) {
        atomicAdd(&gsum[(size_t)curb * HDIM + t], acc);
        if (t == 0) atomicAdd(&gcnt[curb], (float)cnt);
    }
}

// per-graph MLP head (fp32)
__global__ __launch_bounds__(256) void mlp_head(const float* __restrict__ gsum,
                                                const float* __restrict__ gcnt,
                                                const float* __restrict__ lw1,
                                                const float* __restrict__ lb1,
                                                const float* __restrict__ lw2,
                                                const float* __restrict__ lb2,
                                                float* __restrict__ out) {
    __shared__ float g[HDIM];
    __shared__ float hid[HDIM];
    int b = blockIdx.x, t = threadIdx.x;
    float cnt = fmaxf(gcnt[b], 1.f);
    g[t] = gsum[(size_t)b * HDIM + t] / cnt;
    __syncthreads();
    float acc = lb1[t];
    for (int k = 0; k < HDIM; ++k) acc += g[k] * lw1[(size_t)k * HDIM + t];
    hid[t] = leaky(acc, ACT_SLOPE);
    __syncthreads();
    if (t < C_OUT) {
        float o = lb2[t];
        for (int k = 0; k < HDIM; ++k) o += hid[k] * lw2[(size_t)k * C_OUT + t];
        out[(size_t)b * C_OUT + t] = o;
    }
}

extern "C" void kernel_launch(void* const* d_in, const int* in_sizes, int n_in,
                              void* d_out, int out_size, void* d_ws, size_t ws_size,
                              hipStream_t stream) {
    const float* x      = (const float*)d_in[0];
    const int*   ei     = (const int*)d_in[1];
    const int*   batch  = (const int*)d_in[2];
    const float* W1     = (const float*)d_in[4];
    const float* a_src1 = (const float*)d_in[5];
    const float* a_dst1 = (const float*)d_in[6];
    const float* b1     = (const float*)d_in[7];
    const float* gamma  = (const float*)d_in[8];
    const float* beta   = (const float*)d_in[9];
    const float* W2     = (const float*)d_in[10];
    const float* a_src2 = (const float*)d_in[11];
    const float* a_dst2 = (const float*)d_in[12];
    const float* b2     = (const float*)d_in[13];
    const float* lw1    = (const float*)d_in[14];
    const float* lb1    = (const float*)d_in[15];
    const float* lw2    = (const float*)d_in[16];
    const float* lb2    = (const float*)d_in[17];
    float* out = (float*)d_out;

    const size_t NH = (size_t)N_NODES * HDIM;
    char* ws = (char*)d_ws;
    unsigned short* hbf     = (unsigned short*)ws; ws += NH * 2;
    unsigned short* aggbf   = (unsigned short*)ws; ws += NH * 2;
    unsigned short* Wt1     = (unsigned short*)ws; ws += 65536 * 2;
    unsigned short* Wt2f    = (unsigned short*)ws; ws += 65536 * 2;
    float* es      = (float*)ws; ws += N_NODES * 4;
    float* ed      = (float*)ws; ws += N_NODES * 4;
    float* csum    = (float*)ws; ws += HDIM * 4;
    float* csq     = (float*)ws; ws += HDIM * 4;
    float* scale   = (float*)ws; ws += HDIM * 4;
    float* shift   = (float*)ws; ws += HDIM * 4;
    float* cbias   = (float*)ws; ws += HDIM * 4;
    float* gsum    = (float*)ws; ws += NGRAPH * HDIM * 4;
    float* gcnt    = (float*)ws; ws += NGRAPH * 4;
    int*   row_ptr = (int*)ws;   ws += (N_NODES + 1) * 4;
    int*   bcnt    = (int*)ws;   ws += NBUCK * 4;
    int*   bbase   = (int*)ws;   ws += NBUCK * 4;
    int*   hist2d  = (int*)ws;   ws += (size_t)SORT_NB * NBUCK * 4;
    int*   csr_src = (int*)ws;   ws += (size_t)ETOT * 4;
    int*   bstore  = (int*)ws;   ws += (size_t)NBUCK * BCAP * 4;

    const int agg_blocks = (N_NODES + 7) / 8;   // 6250
    const int gemm_blocks = (N_NODES + 127) / 128;

    // ---- atomic-free CSR build (once; shared by both convs) ----
    count_k<<<SORT_NB, 256, 0, stream>>>(ei, hist2d);
    colscan_k<<<(NBUCK + 255) / 256, 256, 0, stream>>>(hist2d, bcnt);
    scan_buckets<<<1, 256, 0, stream>>>(bcnt, bbase, row_ptr);
    scatter2_k<<<SORT_NB, 256, 0, stream>>>(ei, hist2d, bstore);
    place_k<<<NBUCK, 256, 0, stream>>>(bcnt, bbase, bstore, row_ptr, csr_src);

    // ---- weight prep (W1 only; W2 handled by fold_bn) ----
    prep_w<<<256, 256, 0, stream>>>(W1, Wt1);

    // ---- conv1: GEMM (fp32 A conversion fused, +dots) -> softmax-gather ----
    gemm_bf16<true><<<gemm_blocks, 512, 0, stream>>>(x, Wt1, nullptr,
                                                     a_src1, a_dst1, es, ed, hbf, N_NODES);
    dst_agg<<<agg_blocks, 256, 0, stream>>>(row_ptr, csr_src, es, ed, hbf, b1, aggbf);

    // ---- BN stats/params + fold into W2 ----
    hipMemsetAsync(csum, 0, HDIM * 8, stream);               // csum + csq (adjacent)
    bn_stats_k<<<256, 256, 0, stream>>>(aggbf, csum, csq);
    bn_param<<<1, 256, 0, stream>>>(csum, csq, gamma, beta, scale, shift);
    fold_bn<<<256, 256, 0, stream>>>(W2, scale, shift, Wt2f, cbias);

    // ---- conv2: GEMM (BN folded into weights + rank-1 bias, +dots) -> softmax-gather ----
    gemm_bf16<false><<<gemm_blocks, 512, 0, stream>>>(aggbf, Wt2f, cbias,
                                                      a_src2, a_dst2, es, ed, hbf, N_NODES);
    dst_agg<<<agg_blocks, 256, 0, stream>>>(row_ptr, csr_src, es, ed, hbf, b2, aggbf);

    // ---- pool ----
    hipMemsetAsync(gsum, 0, (size_t)(NGRAPH * HDIM + NGRAPH) * 4, stream);  // gsum + gcnt
    post_pool<<<256, 256, 0, stream>>>(aggbf, batch, gsum, gcnt);

    // ---- MLP head ----
    mlp_head<<<NGRAPH, 256, 0, stream>>>(gsum, gcnt, lw1, lb1, lw2, lb2, out);
}

// Round 13
// 333.144 us; speedup vs baseline: 1.0262x; 1.0262x over previous
//
#include <hip/hip_runtime.h>
#include <math.h>

#define N_NODES 50000
#define N_EDGES 800000
#define ETOT    (N_EDGES + N_NODES)
#define FDIM    256
#define HDIM    256
#define NGRAPH  64
#define C_OUT   10
#define BN_EPS  1e-5f
#define ATT_SLOPE 0.2f
#define ACT_SLOPE 0.01f

#define NBUCK   ((N_NODES + 15) / 16)    // 3125 buckets of 16 dsts
#define BCAP    512                      // bucket capacity (mean 272)
#define SORT_NB 192                      // blocks for count/scatter passes
#define EPB     ((ETOT + SORT_NB - 1) / SORT_NB)

typedef __attribute__((ext_vector_type(8))) short bf16x8;
typedef __attribute__((ext_vector_type(4))) float f32x4;

__device__ __forceinline__ float leaky(float x, float s) { return x >= 0.f ? x : s * x; }

__device__ __forceinline__ float bf2f(unsigned short u) {
    return __uint_as_float((unsigned)u << 16);
}
__device__ __forceinline__ unsigned short f2bf(float f) {
    unsigned u = __float_as_uint(f);
    u += 0x7FFF + ((u >> 16) & 1);   // RNE
    return (unsigned short)(u >> 16);
}
__device__ __forceinline__ float rlF(float a, int j) {
    return __uint_as_float(__builtin_amdgcn_readlane(__float_as_uint(a), j));
}

// async global->LDS, 16B per lane; dst must be wave-uniform base (lane*16 auto-offset)
__device__ __forceinline__ void gload_lds16(const unsigned short* g, unsigned short* l) {
    __builtin_amdgcn_global_load_lds((const __attribute__((address_space(1))) void*)(g),
                                     (__attribute__((address_space(3))) void*)(l), 16, 0, 0);
}

__device__ __forceinline__ void edge_sd(const int* __restrict__ ei, int e, int& s, int& d) {
    if (e < N_EDGES) { s = ei[e]; d = ei[N_EDGES + e]; }
    else             { s = e - N_EDGES; d = s; }
}

// ---------------- weight prep: W1^T->bf16 (W2 handled by fold_bn) ----------------
__global__ __launch_bounds__(256) void prep_w(const float* __restrict__ W1,
                                              unsigned short* __restrict__ Wt1) {
    int idx = blockIdx.x * 256 + threadIdx.x;
    int n = idx >> 8, k = idx & 255;
    Wt1[idx] = f2bf(W1[k * 256 + n]);
}

// ---------------- BN fold: Wt2f[n][k] = bf16(scale[k]*W2[k][n]); cbias[n] = sum_k shift[k]*W2[k][n]
__global__ __launch_bounds__(256) void fold_bn(const float* __restrict__ W2,
                                               const float* __restrict__ scale,
                                               const float* __restrict__ shift,
                                               unsigned short* __restrict__ Wt2f,
                                               float* __restrict__ cbias) {
    __shared__ float red[256];
    int n = blockIdx.x, k = threadIdx.x;
    float w = W2[k * 256 + n];
    Wt2f[n * 256 + k] = f2bf(w * scale[k]);
    red[k] = w * shift[k];
    __syncthreads();
    #pragma unroll
    for (int off = 128; off; off >>= 1) {
        if (k < off) red[k] += red[k + off];
        __syncthreads();
    }
    if (k == 0) cbias[n] = red[0];
}

// ---------------- bf16 MFMA GEMM, 128x256 row-strip tile, 512 threads (8 waves 2x4) ----------------
template<bool FROMF32>
__global__ __launch_bounds__(512) void gemm_bf16(const void* __restrict__ Avp,
                                                 const unsigned short* __restrict__ Bt,
                                                 const float* __restrict__ cbias,
                                                 const float* __restrict__ avs,
                                                 const float* __restrict__ avd,
                                                 float* __restrict__ es,
                                                 float* __restrict__ ed,
                                                 unsigned short* __restrict__ C, int M) {
    __shared__ unsigned short Al[128 * 64];
    __shared__ unsigned short Bl[256 * 64];
    __shared__ float lred[4][128][2];
    const int tid = threadIdx.x;
    const int lane = tid & 63;
    const int wid = tid >> 6;            // 0..7
    const int wm = wid >> 2, wn = wid & 3;
    const int row0 = blockIdx.x * 128;
    const int g = lane >> 4, rl = lane & 15;

    f32x4 acc[4][4];
    #pragma unroll
    for (int m = 0; m < 4; ++m)
        #pragma unroll
        for (int n = 0; n < 4; ++n)
            acc[m][n] = (f32x4){0.f, 0.f, 0.f, 0.f};

    for (int kk = 0; kk < 256; kk += 64) {
        // ---- stage A ----
        if (FROMF32) {
            const float* Af = (const float*)Avp;
            #pragma unroll
            for (int j = 0; j < 2; ++j) {
                int idx = j * 512 + tid;
                int row = idx >> 3, chunk = idx & 7;
                int sc = chunk ^ (row & 7);
                int grow = row0 + row; if (grow >= M) grow = M - 1;
                float4 f0 = *(const float4*)&Af[(size_t)grow * 256 + kk + chunk * 8];
                float4 f1 = *(const float4*)&Af[(size_t)grow * 256 + kk + chunk * 8 + 4];
                uint4 av;
                unsigned short* p = (unsigned short*)&av;
                p[0] = f2bf(f0.x); p[1] = f2bf(f0.y); p[2] = f2bf(f0.z); p[3] = f2bf(f0.w);
                p[4] = f2bf(f1.x); p[5] = f2bf(f1.y); p[6] = f2bf(f1.z); p[7] = f2bf(f1.w);
                *(uint4*)&Al[row * 64 + sc * 8] = av;
            }
        } else {
            const unsigned short* Ab = (const unsigned short*)Avp;
            #pragma unroll
            for (int j = 0; j < 2; ++j) {
                int rowBase = (j * 8 + wid) * 8;
                int row = rowBase + (lane >> 3);
                int grow = row0 + row; if (grow >= M) grow = M - 1;
                int chunk = (lane & 7) ^ (row & 7);
                gload_lds16(&Ab[(size_t)grow * 256 + kk + chunk * 8], &Al[rowBase * 64]);
            }
        }
        // ---- stage B via global_load_lds (pre-swizzled source) ----
        #pragma unroll
        for (int j = 0; j < 4; ++j) {
            int colBase = (j * 8 + wid) * 8;
            int col = colBase + (lane >> 3);
            int chunk = (lane & 7) ^ (col & 7);
            gload_lds16(&Bt[(size_t)col * 256 + kk + chunk * 8], &Bl[colBase * 64]);
        }
        __syncthreads();
        #pragma unroll
        for (int ks = 0; ks < 2; ++ks) {
            bf16x8 af[4], bfr[4];
            int chunk = ks * 4 + g;
            #pragma unroll
            for (int m = 0; m < 4; ++m) {
                int row = wm * 64 + m * 16 + rl;
                int sc = chunk ^ (row & 7);
                af[m] = *(const bf16x8*)&Al[row * 64 + sc * 8];
            }
            #pragma unroll
            for (int n = 0; n < 4; ++n) {
                int col = wn * 64 + n * 16 + rl;
                int sc = chunk ^ (col & 7);
                bfr[n] = *(const bf16x8*)&Bl[col * 64 + sc * 8];
            }
            #pragma unroll
            for (int m = 0; m < 4; ++m)
                #pragma unroll
                for (int n = 0; n < 4; ++n)
                    acc[m][n] = __builtin_amdgcn_mfma_f32_16x16x32_bf16(af[m], bfr[n], acc[m][n], 0, 0, 0);
        }
        __syncthreads();
    }
    // rank-1 BN-fold bias (conv2 only)
    if (cbias != nullptr) {
        #pragma unroll
        for (int n = 0; n < 4; ++n) {
            float cb = cbias[wn * 64 + n * 16 + rl];
            #pragma unroll
            for (int m = 0; m < 4; ++m)
                #pragma unroll
                for (int r = 0; r < 4; ++r)
                    acc[m][n][r] += cb;
        }
    }
    // C write (bf16): C/D frag layout col=lane&15, row=(lane>>4)*4+reg
    #pragma unroll
    for (int m = 0; m < 4; ++m) {
        #pragma unroll
        for (int n = 0; n < 4; ++n) {
            int col = wn * 64 + n * 16 + rl;
            #pragma unroll
            for (int r = 0; r < 4; ++r) {
                int row = row0 + wm * 64 + m * 16 + g * 4 + r;
                if (row < M) C[(size_t)row * 256 + col] = f2bf(acc[m][n][r]);
            }
        }
    }
    // fused attention dots: 16-lane reduce -> LDS (4 wn groups) -> exact plain stores
    float as_[4], ad_[4];
    #pragma unroll
    for (int n = 0; n < 4; ++n) {
        int col = wn * 64 + n * 16 + rl;
        as_[n] = avs[col]; ad_[n] = avd[col];
    }
    #pragma unroll
    for (int m = 0; m < 4; ++m) {
        #pragma unroll
        for (int r = 0; r < 4; ++r) {
            float ps = 0.f, pd = 0.f;
            #pragma unroll
            for (int n = 0; n < 4; ++n) {
                float v = acc[m][n][r];
                ps += v * as_[n]; pd += v * ad_[n];
            }
            #pragma unroll
            for (int off = 1; off < 16; off <<= 1) {
                ps += __shfl_xor(ps, off);
                pd += __shfl_xor(pd, off);
            }
            if (rl == 0) {
                int lr = wm * 64 + m * 16 + g * 4 + r;
                lred[wn][lr][0] = ps;
                lred[wn][lr][1] = pd;
            }
        }
    }
    __syncthreads();
    if (tid < 128) {
        int row = row0 + tid;
        if (row < M) {
            es[row] = (lred[0][tid][0] + lred[1][tid][0]) + (lred[2][tid][0] + lred[3][tid][0]);
            ed[row] = (lred[0][tid][1] + lred[1][tid][1]) + (lred[2][tid][1] + lred[3][tid][1]);
        }
    }
}

// ---------------- atomic-free CSR build (2-pass LDS-histogram bucket sort) ----------------
__global__ __launch_bounds__(256) void count_k(const int* __restrict__ ei,
                                               int* __restrict__ hist2d) {
    __shared__ int lcnt[NBUCK];
    int t = threadIdx.x, blk = blockIdx.x;
    for (int i = t; i < NBUCK; i += 256) lcnt[i] = 0;
    __syncthreads();
    int e0 = blk * EPB, e1 = min(e0 + EPB, ETOT);
    for (int e = e0 + t; e < e1; e += 256) {
        int d = (e < N_EDGES) ? ei[N_EDGES + e] : (e - N_EDGES);
        atomicAdd(&lcnt[d >> 4], 1);
    }
    __syncthreads();
    int* outp = hist2d + blk * NBUCK;
    for (int i = t; i < NBUCK; i += 256) outp[i] = lcnt[i];
}

__global__ __launch_bounds__(256) void colscan_k(int* __restrict__ hist2d,
                                                 int* __restrict__ bcnt) {
    int col = blockIdx.x * 256 + threadIdx.x;
    if (col >= NBUCK) return;
    int run = 0;
    for (int b = 0; b < SORT_NB; ++b) {
        int idx = b * NBUCK + col;
        int c = hist2d[idx];
        hist2d[idx] = run;
        run += c;
    }
    bcnt[col] = run;
}

__global__ __launch_bounds__(256) void scan_buckets(const int* __restrict__ bcnt,
                                                    int* __restrict__ bbase,
                                                    int* __restrict__ row_ptr) {
    __shared__ int s[256];
    constexpr int PER = (NBUCK + 255) / 256;   // 13
    int t = threadIdx.x;
    int loc[PER];
    int sum = 0;
    #pragma unroll
    for (int i = 0; i < PER; ++i) {
        int idx = t * PER + i;
        loc[i] = sum;
        sum += (idx < NBUCK) ? bcnt[idx] : 0;
    }
    s[t] = sum;
    __syncthreads();
    #pragma unroll
    for (int off = 1; off < 256; off <<= 1) {
        int add = (t >= off) ? s[t - off] : 0;
        __syncthreads();
        s[t] += add;
        __syncthreads();
    }
    int base = (t > 0) ? s[t - 1] : 0;
    #pragma unroll
    for (int i = 0; i < PER; ++i) {
        int idx = t * PER + i;
        if (idx < NBUCK) bbase[idx] = base + loc[i];
    }
    if (t == 0) row_ptr[N_NODES] = ETOT;
}

__global__ __launch_bounds__(256) void scatter2_k(const int* __restrict__ ei,
                                                  const int* __restrict__ hist2d,
                                                  int* __restrict__ bstore) {
    __shared__ int lcur[NBUCK];
    __shared__ int lbase[NBUCK];
    int t = threadIdx.x, blk = blockIdx.x;
    const int* boff = hist2d + blk * NBUCK;
    for (int i = t; i < NBUCK; i += 256) { lcur[i] = 0; lbase[i] = boff[i]; }
    __syncthreads();
    int e0 = blk * EPB, e1 = min(e0 + EPB, ETOT);
    for (int e = e0 + t; e < e1; e += 256) {
        int s, d; edge_sd(ei, e, s, d);
        int b = d >> 4;
        int r = atomicAdd(&lcur[b], 1);
        int pos = lbase[b] + r;
        if (pos < BCAP) bstore[(size_t)b * BCAP + pos] = s | ((d & 15) << 16);
    }
}

__global__ __launch_bounds__(256) void place_k(const int* __restrict__ bcnt,
                                               const int* __restrict__ bbase,
                                               const int* __restrict__ bstore,
                                               int* __restrict__ row_ptr,
                                               int* __restrict__ csr_src) {
    __shared__ int h16[16], e16[16], c16[16];
    int b = blockIdx.x, t = threadIdx.x;
    if (t < 16) { h16[t] = 0; c16[t] = 0; }
    __syncthreads();
    int sz = bcnt[b]; if (sz > BCAP) sz = BCAP;
    int base = bbase[b];
    const int* bs = bstore + (size_t)b * BCAP;
    int v0 = -1, v1 = -1;
    if (t < sz)       { v0 = bs[t];       atomicAdd(&h16[v0 >> 16], 1); }
    if (t + 256 < sz) { v1 = bs[t + 256]; atomicAdd(&h16[v1 >> 16], 1); }
    __syncthreads();
    if (t == 0) {
        int run = 0;
        #pragma unroll
        for (int j = 0; j < 16; ++j) { e16[j] = run; run += h16[j]; }
    }
    __syncthreads();
    if (t < 16) {
        int d = b * 16 + t;
        if (d < N_NODES) row_ptr[d] = base + e16[t];
    }
    if (v0 >= 0) {
        int dl = v0 >> 16;
        int pos = base + e16[dl] + atomicAdd(&c16[dl], 1);
        csr_src[pos] = v0 & 0xFFFF;
    }
    if (v1 >= 0) {
        int dl = v1 >> 16;
        int pos = base + e16[dl] + atomicAdd(&c16[dl], 1);
        csr_src[pos] = v1 & 0xFFFF;
    }
}

// ---------------- gather helper: 4-deep ILP, wave-uniform readlane broadcast ----------------
__device__ __forceinline__ void gather4(const unsigned short* __restrict__ hl,
                                        float a, int src, int lim,
                                        float4& A0, float4& A1, float4& A2, float4& A3) {
    int j = 0;
    for (; j + 3 < lim; j += 4) {
        float w0 = rlF(a, j + 0), w1 = rlF(a, j + 1), w2 = rlF(a, j + 2), w3 = rlF(a, j + 3);
        int s0 = __builtin_amdgcn_readlane(src, j + 0);
        int s1 = __builtin_amdgcn_readlane(src, j + 1);
        int s2 = __builtin_amdgcn_readlane(src, j + 2);
        int s3 = __builtin_amdgcn_readlane(src, j + 3);
        ushort4 v0 = *(const ushort4*)&hl[(size_t)s0 * HDIM];
        ushort4 v1 = *(const ushort4*)&hl[(size_t)s1 * HDIM];
        ushort4 v2 = *(const ushort4*)&hl[(size_t)s2 * HDIM];
        ushort4 v3 = *(const ushort4*)&hl[(size_t)s3 * HDIM];
        A0.x += w0 * bf2f(v0.x); A0.y += w0 * bf2f(v0.y); A0.z += w0 * bf2f(v0.z); A0.w += w0 * bf2f(v0.w);
        A1.x += w1 * bf2f(v1.x); A1.y += w1 * bf2f(v1.y); A1.z += w1 * bf2f(v1.z); A1.w += w1 * bf2f(v1.w);
        A2.x += w2 * bf2f(v2.x); A2.y += w2 * bf2f(v2.y); A2.z += w2 * bf2f(v2.z); A2.w += w2 * bf2f(v2.w);
        A3.x += w3 * bf2f(v3.x); A3.y += w3 * bf2f(v3.y); A3.z += w3 * bf2f(v3.z); A3.w += w3 * bf2f(v3.w);
    }
    for (; j < lim; ++j) {
        float w = rlF(a, j);
        int s = __builtin_amdgcn_readlane(src, j);
        ushort4 v = *(const ushort4*)&hl[(size_t)s * HDIM];
        A0.x += w * bf2f(v.x); A0.y += w * bf2f(v.y); A0.z += w * bf2f(v.z); A0.w += w * bf2f(v.w);
    }
}

// ---------------- fused per-dst softmax + bf16 gather + bias + leaky -> bf16 ----------------
__global__ __launch_bounds__(256) void dst_agg(const int* __restrict__ row_ptr,
                                               const int* __restrict__ csr_src,
                                               const float* __restrict__ es,
                                               const float* __restrict__ ed,
                                               const unsigned short* __restrict__ h,
                                               const float* __restrict__ bias,
                                               unsigned short* __restrict__ outb) {
    int d = blockIdx.x * 4 + (threadIdx.x >> 6);
    int lane = threadIdx.x & 63;
    if (d >= N_NODES) return;
    float4 b4 = *(const float4*)&bias[lane * 4];
    int start = row_ptr[d], end = row_ptr[d + 1];
    int deg = end - start;
    float edv = ed[d];
    const unsigned short* hl = h + lane * 4;
    float4 A0 = {0,0,0,0}, A1 = {0,0,0,0}, A2 = {0,0,0,0}, A3 = {0,0,0,0};
    float ssum = 0.f;

    if (deg > 0 && deg <= 64) {
        int src = 0; float v = -INFINITY;
        if (lane < deg) {
            src = csr_src[start + lane];
            v = leaky(es[src] + edv, ATT_SLOPE);
        }
        float m = v;
        #pragma unroll
        for (int off = 32; off; off >>= 1) m = fmaxf(m, __shfl_xor(m, off));
        float a = (lane < deg) ? expf(v - m) : 0.f;
        ssum = a;
        gather4(hl, a, src, deg, A0, A1, A2, A3);
    } else if (deg > 64) {
        float m = -INFINITY;
        for (int base = start; base < end; base += 64) {
            int idx = base + lane;
            if (idx < end) m = fmaxf(m, leaky(es[csr_src[idx]] + edv, ATT_SLOPE));
        }
        #pragma unroll
        for (int off = 32; off; off >>= 1) m = fmaxf(m, __shfl_xor(m, off));
        for (int base = start; base < end; base += 64) {
            int idx = base + lane;
            int src = 0; float a = 0.f;
            if (idx < end) {
                src = csr_src[idx];
                a = expf(leaky(es[src] + edv, ATT_SLOPE) - m);
            }
            ssum += a;
            int lim = end - base; if (lim > 64) lim = 64;
            gather4(hl, a, src, lim, A0, A1, A2, A3);
        }
    } else {
        ssum = 1.f;
    }
    #pragma unroll
    for (int off = 32; off; off >>= 1) ssum += __shfl_xor(ssum, off);
    float inv = (deg > 0) ? (1.f / ssum) : 0.f;
    float4 acc;
    acc.x = (A0.x + A1.x) + (A2.x + A3.x);
    acc.y = (A0.y + A1.y) + (A2.y + A3.y);
    acc.z = (A0.z + A1.z) + (A2.z + A3.z);
    acc.w = (A0.w + A1.w) + (A2.w + A3.w);
    ushort4 o;
    o.x = f2bf(leaky(acc.x * inv + b4.x, ACT_SLOPE));
    o.y = f2bf(leaky(acc.y * inv + b4.y, ACT_SLOPE));
    o.z = f2bf(leaky(acc.z * inv + b4.z, ACT_SLOPE));
    o.w = f2bf(leaky(acc.w * inv + b4.w, ACT_SLOPE));
    *(ushort4*)&outb[(size_t)d * HDIM + lane * 4] = o;
}

// column sum/sumsq over bf16 activations (read-only)
__global__ __launch_bounds__(256) void bn_stats_k(const unsigned short* __restrict__ buf,
                                                  float* __restrict__ csum,
                                                  float* __restrict__ csq) {
    int t = threadIdx.x;
    int rows_per = (N_NODES + gridDim.x - 1) / gridDim.x;
    int r0 = blockIdx.x * rows_per;
    int r1 = min(r0 + rows_per, N_NODES);
    float sum = 0.f, sq = 0.f;
    for (int r = r0; r < r1; ++r) {
        float v = bf2f(buf[(size_t)r * HDIM + t]);
        sum += v; sq += v * v;
    }
    atomicAdd(&csum[t], sum);
    atomicAdd(&csq[t], sq);
}

__global__ __launch_bounds__(256) void bn_param(const float* __restrict__ csum,
                                                const float* __restrict__ csq,
                                                const float* __restrict__ gamma,
                                                const float* __restrict__ beta,
                                                float* __restrict__ scale,
                                                float* __restrict__ shift) {
    int t = threadIdx.x;
    float mean = csum[t] / (float)N_NODES;
    float var = csq[t] / (float)N_NODES - mean * mean;
    float sc = gamma[t] * rsqrtf(var + BN_EPS);
    scale[t] = sc;
    shift[t] = beta[t] - mean * sc;
}

// run-length pooled segment add over bf16 activations
__global__ __launch_bounds__(256) void post_pool(const unsigned short* __restrict__ buf,
                                                 const int* __restrict__ batch,
                                                 float* __restrict__ gsum,
                                                 float* __restrict__ gcnt) {
    int t = threadIdx.x;
    int rows_per = (N_NODES + gridDim.x - 1) / gridDim.x;
    int r0 = blockIdx.x * rows_per;
    int r1 = min(r0 + rows_per, N_NODES);
    if (r0 >= r1) return;
    int curb = -1; float acc = 0.f; int cnt = 0;
    for (int r = r0; r < r1; ++r) {
        int bb = batch[r];
        if (bb != curb) {
            if (curb >= 0) {
                atomicAdd(&gsum[(size_t)curb * HDIM + t], acc);
                if (t == 0) atomicAdd(&gcnt[curb], (float)cnt);
            }
            curb = bb; acc = 0.f; cnt = 0;
        }
        acc += bf2f(buf[(size_t)r * HDIM + t]);
        cnt++;
    }
    if (curb >= 0) {
        atomicAdd(&gsum[(size_t)curb * HDIM + t], acc);
        if (t == 0) atomicAdd(&gcnt[curb], (float)cnt);
    }
}

// per-graph MLP head (fp32)
__global__ __launch_bounds__(256) void mlp_head(const float* __restrict__ gsum,
                                                const float* __restrict__ gcnt,
                                                const float* __restrict__ lw1,
                                                const float* __restrict__ lb1,
                                                const float* __restrict__ lw2,
                                                const float* __restrict__ lb2,
                                                float* __restrict__ out) {
    __shared__ float g[HDIM];
    __shared__ float hid[HDIM];
    int b = blockIdx.x, t = threadIdx.x;
    float cnt = fmaxf(gcnt[b], 1.f);
    g[t] = gsum[(size_t)b * HDIM + t] / cnt;
    __syncthreads();
    float acc = lb1[t];
    for (int k = 0; k < HDIM; ++k) acc += g[k] * lw1[(size_t)k * HDIM + t];
    hid[t] = leaky(acc, ACT_SLOPE);
    __syncthreads();
    if (t < C_OUT) {
        float o = lb2[t];
        for (int k = 0; k < HDIM; ++k) o += hid[k] * lw2[(size_t)k * C_OUT + t];
        out[(size_t)b * C_OUT + t] = o;
    }
}

extern "C" void kernel_launch(void* const* d_in, const int* in_sizes, int n_in,
                              void* d_out, int out_size, void* d_ws, size_t ws_size,
                              hipStream_t stream) {
    const float* x      = (const float*)d_in[0];
    const int*   ei     = (const int*)d_in[1];
    const int*   batch  = (const int*)d_in[2];
    const float* W1     = (const float*)d_in[4];
    const float* a_src1 = (const float*)d_in[5];
    const float* a_dst1 = (const float*)d_in[6];
    const float* b1     = (const float*)d_in[7];
    const float* gamma  = (const float*)d_in[8];
    const float* beta   = (const float*)d_in[9];
    const float* W2     = (const float*)d_in[10];
    const float* a_src2 = (const float*)d_in[11];
    const float* a_dst2 = (const float*)d_in[12];
    const float* b2     = (const float*)d_in[13];
    const float* lw1    = (const float*)d_in[14];
    const float* lb1    = (const float*)d_in[15];
    const float* lw2    = (const float*)d_in[16];
    const float* lb2    = (const float*)d_in[17];
    float* out = (float*)d_out;

    const size_t NH = (size_t)N_NODES * HDIM;
    char* ws = (char*)d_ws;
    unsigned short* hbf     = (unsigned short*)ws; ws += NH * 2;
    unsigned short* aggbf   = (unsigned short*)ws; ws += NH * 2;
    unsigned short* Wt1     = (unsigned short*)ws; ws += 65536 * 2;
    unsigned short* Wt2f    = (unsigned short*)ws; ws += 65536 * 2;
    float* es      = (float*)ws; ws += N_NODES * 4;
    float* ed      = (float*)ws; ws += N_NODES * 4;
    float* csum    = (float*)ws; ws += HDIM * 4;
    float* csq     = (float*)ws; ws += HDIM * 4;
    float* scale   = (float*)ws; ws += HDIM * 4;
    float* shift   = (float*)ws; ws += HDIM * 4;
    float* cbias   = (float*)ws; ws += HDIM * 4;
    float* gsum    = (float*)ws; ws += NGRAPH * HDIM * 4;
    float* gcnt    = (float*)ws; ws += NGRAPH * 4;
    int*   row_ptr = (int*)ws;   ws += (N_NODES + 1) * 4;
    int*   bcnt    = (int*)ws;   ws += NBUCK * 4;
    int*   bbase   = (int*)ws;   ws += NBUCK * 4;
    int*   hist2d  = (int*)ws;   ws += (size_t)SORT_NB * NBUCK * 4;
    int*   csr_src = (int*)ws;   ws += (size_t)ETOT * 4;
    int*   bstore  = (int*)ws;   ws += (size_t)NBUCK * BCAP * 4;

    const int wave4_blocks = (N_NODES + 3) / 4;   // 12500
    const int gemm_blocks = (N_NODES + 127) / 128;

    // ---- atomic-free CSR build (once; shared by both convs) ----
    count_k<<<SORT_NB, 256, 0, stream>>>(ei, hist2d);
    colscan_k<<<(NBUCK + 255) / 256, 256, 0, stream>>>(hist2d, bcnt);
    scan_buckets<<<1, 256, 0, stream>>>(bcnt, bbase, row_ptr);
    scatter2_k<<<SORT_NB, 256, 0, stream>>>(ei, hist2d, bstore);
    place_k<<<NBUCK, 256, 0, stream>>>(bcnt, bbase, bstore, row_ptr, csr_src);

    // ---- weight prep (W1 only; W2 handled by fold_bn) ----
    prep_w<<<256, 256, 0, stream>>>(W1, Wt1);

    // ---- conv1: GEMM (fp32 A conversion fused, +dots) -> softmax-gather ----
    gemm_bf16<true><<<gemm_blocks, 512, 0, stream>>>(x, Wt1, nullptr,
                                                     a_src1, a_dst1, es, ed, hbf, N_NODES);
    dst_agg<<<wave4_blocks, 256, 0, stream>>>(row_ptr, csr_src, es, ed, hbf, b1, aggbf);

    // ---- BN stats/params + fold into W2 ----
    hipMemsetAsync(csum, 0, HDIM * 8, stream);               // csum + csq (adjacent)
    bn_stats_k<<<256, 256, 0, stream>>>(aggbf, csum, csq);
    bn_param<<<1, 256, 0, stream>>>(csum, csq, gamma, beta, scale, shift);
    fold_bn<<<256, 256, 0, stream>>>(W2, scale, shift, Wt2f, cbias);

    // ---- conv2: GEMM (BN folded into weights + rank-1 bias, +dots) -> softmax-gather ----
    gemm_bf16<false><<<gemm_blocks, 512, 0, stream>>>(aggbf, Wt2f, cbias,
                                                      a_src2, a_dst2, es, ed, hbf, N_NODES);
    dst_agg<<<wave4_blocks, 256, 0, stream>>>(row_ptr, csr_src, es, ed, hbf, b2, aggbf);

    // ---- pool ----
    hipMemsetAsync(gsum, 0, (size_t)(NGRAPH * HDIM + NGRAPH) * 4, stream);  // gsum + gcnt
    post_pool<<<256, 256, 0, stream>>>(aggbf, batch, gsum, gcnt);

    // ---- MLP head ----
    mlp_head<<<NGRAPH, 256, 0, stream>>>(gsum, gcnt, lw1, lb1, lw2, lb2, out);
}